// Round 1
// baseline (574.664 us; speedup 1.0000x reference)
//
#include <hip/hip_runtime.h>
#include <hip/hip_bf16.h>
#include <math.h>

#define NE    8
#define KTOP  2
#define CDIM  1024
#define HDIM  4096
#define NTOK  8192
#define CAPE  1280
#define NSLOT (NTOK * KTOP)

typedef __bf16 bf16x8 __attribute__((ext_vector_type(8)));
typedef __bf16 bf16x4 __attribute__((ext_vector_type(4)));
typedef float  f32x4  __attribute__((ext_vector_type(4)));

// ---------------------------------------------------------------------------
// Transposing fp32 -> bf16 weight conversion: src [E][R][Cc] -> dst [E][Cc][R]
// ---------------------------------------------------------------------------
__global__ __launch_bounds__(256) void k_transpose_bf16(
    const float* __restrict__ src, __bf16* __restrict__ dst, int R, int Cc)
{
    __shared__ float tile[32][33];
    const int e  = blockIdx.z;
    const int cb = blockIdx.x * 32;
    const int rb = blockIdx.y * 32;
    const int tx = threadIdx.x, ty = threadIdx.y;
    const float* s = src + (size_t)e * R * Cc;
    __bf16*      d = dst + (size_t)e * R * Cc;
#pragma unroll
    for (int i = 0; i < 32; i += 8)
        tile[ty + i][tx] = s[(size_t)(rb + ty + i) * Cc + cb + tx];
    __syncthreads();
#pragma unroll
    for (int i = 0; i < 32; i += 8)
        d[(size_t)(cb + ty + i) * R + rb + tx] = (__bf16)tile[tx][ty + i];
}

// ---------------------------------------------------------------------------
// Router: fp32 logits -> softmax -> top2 -> normalized gates. 1 wave = 1 token.
// ---------------------------------------------------------------------------
__global__ __launch_bounds__(256) void k_router(
    const float* __restrict__ x, const float* __restrict__ rw,
    const float* __restrict__ rb, float* __restrict__ probs,
    float* __restrict__ gates, int* __restrict__ tidx)
{
    __shared__ float rws[NE * CDIM];
    const int tid = threadIdx.x;
    for (int i = tid; i < NE * CDIM / 4; i += 256)
        ((float4*)rws)[i] = ((const float4*)rw)[i];
    __syncthreads();

    const int wave = tid >> 6, lane = tid & 63;
    const int n = blockIdx.x * 4 + wave;
    const float* xr = x + (size_t)n * CDIM;

    float acc[NE];
#pragma unroll
    for (int e = 0; e < NE; ++e) acc[e] = 0.f;
    for (int j = 0; j < CDIM / 64; ++j) {
        const float xv = xr[j * 64 + lane];
#pragma unroll
        for (int e = 0; e < NE; ++e) acc[e] += xv * rws[e * CDIM + j * 64 + lane];
    }
#pragma unroll
    for (int off = 32; off > 0; off >>= 1) {
#pragma unroll
        for (int e = 0; e < NE; ++e) acc[e] += __shfl_down(acc[e], off);
    }
    if (lane == 0) {
        float mx = -1e30f;
#pragma unroll
        for (int e = 0; e < NE; ++e) { acc[e] += rb[e]; mx = fmaxf(mx, acc[e]); }
        float p[NE], s = 0.f;
#pragma unroll
        for (int e = 0; e < NE; ++e) { p[e] = expf(acc[e] - mx); s += p[e]; }
        const float inv = 1.f / s;
#pragma unroll
        for (int e = 0; e < NE; ++e) { p[e] *= inv; probs[(size_t)n * NE + e] = p[e]; }
        int   i1 = 0;  float v1 = p[0];
        int   i2 = -1; float v2 = -1.f;
#pragma unroll
        for (int e = 1; e < NE; ++e) {
            if (p[e] > v1)      { v2 = v1; i2 = i1; v1 = p[e]; i1 = e; }
            else if (p[e] > v2) { v2 = p[e]; i2 = e; }
        }
        const float gs = 1.f / (v1 + v2);
        gates[n * 2 + 0] = v1 * gs;  gates[n * 2 + 1] = v2 * gs;
        tidx[n * 2 + 0]  = i1;       tidx[n * 2 + 1]  = i2;
    }
}

// ---------------------------------------------------------------------------
// Single-block scan: exact slot-order ranks, capacity drop, tok_buf, aux loss.
// ---------------------------------------------------------------------------
__global__ __launch_bounds__(256) void k_scan(
    const int* __restrict__ tidx, const float* __restrict__ probs,
    int* __restrict__ slot, int* __restrict__ tok, float* __restrict__ d_aux)
{
    __shared__ int   lcnt[256][NE];
    __shared__ float ps[256][NE];
    const int t = threadIdx.x;

    for (int i = t; i < NE * CAPE; i += 256) tok[i] = 0;

    int c8[NE];
#pragma unroll
    for (int e = 0; e < NE; ++e) c8[e] = 0;
    const int per  = NSLOT / 256;   // 64
    const int base = t * per;
    for (int s = 0; s < per; ++s) c8[tidx[base + s]]++;
#pragma unroll
    for (int e = 0; e < NE; ++e) lcnt[t][e] = c8[e];

    float f8[NE];
#pragma unroll
    for (int e = 0; e < NE; ++e) f8[e] = 0.f;
    for (int n = t; n < NTOK; n += 256) {
        const float4 a = *(const float4*)(probs + (size_t)n * NE);
        const float4 b = *(const float4*)(probs + (size_t)n * NE + 4);
        f8[0] += a.x; f8[1] += a.y; f8[2] += a.z; f8[3] += a.w;
        f8[4] += b.x; f8[5] += b.y; f8[6] += b.z; f8[7] += b.w;
    }
#pragma unroll
    for (int e = 0; e < NE; ++e) ps[t][e] = f8[e];

    __syncthreads();

    int pre[NE], tot[NE];
#pragma unroll
    for (int e = 0; e < NE; ++e) { pre[e] = 0; tot[e] = 0; }
    for (int tt = 0; tt < 256; ++tt) {
#pragma unroll
        for (int e = 0; e < NE; ++e) {
            const int v = lcnt[tt][e];
            tot[e] += v;
            if (tt < t) pre[e] += v;
        }
    }
    for (int s = 0; s < per; ++s) {
        const int sg = base + s;
        const int e  = tidx[sg];
        const int p  = pre[e]++;
        if (p < CAPE) { slot[sg] = e * CAPE + p; tok[e * CAPE + p] = sg >> 1; }
        else          { slot[sg] = -1; }
    }
    if (t == 0) {
        float imp[NE], isum = 0.f, ld[NE], lsum = 0.f;
#pragma unroll
        for (int e = 0; e < NE; ++e) {
            float v = 0.f;
            for (int tt = 0; tt < 256; ++tt) v += ps[tt][e];
            imp[e] = v; isum += v;
        }
#pragma unroll
        for (int e = 0; e < NE; ++e) { ld[e] = fminf((float)tot[e], (float)CAPE); lsum += ld[e]; }
        float aux = 0.f;
#pragma unroll
        for (int e = 0; e < NE; ++e) aux += (imp[e] / isum) * (ld[e] / lsum);
        *d_aux = aux * (float)(NE * NE);
    }
}

// ---------------------------------------------------------------------------
// Gather tokens into dense per-expert buffers, fp32 -> bf16.
// ---------------------------------------------------------------------------
__global__ __launch_bounds__(256) void k_gather(
    const float* __restrict__ x, const int* __restrict__ tok,
    __bf16* __restrict__ inp)
{
    const int row = blockIdx.x;
    const int t   = threadIdx.x;
    const int tk  = tok[row];
    const float4 v = ((const float4*)(x + (size_t)tk * CDIM))[t];
    bf16x4 o;
    o[0] = (__bf16)v.x; o[1] = (__bf16)v.y; o[2] = (__bf16)v.z; o[3] = (__bf16)v.w;
    *(bf16x4*)(inp + (size_t)row * CDIM + t * 4) = o;
}

// ---------------------------------------------------------------------------
// bf16 MFMA GEMM, B^T input: C[M][N] = A[M][K] * B^T[N][K], per-expert B.
// 128x128 tile, BK=64, 4 waves, global_load_lds(16B) staging.
// GELU: out = gelu(acc + bias) else out = acc. Output bf16.
// ---------------------------------------------------------------------------
template <bool GELU>
__global__ __launch_bounds__(256) void k_gemm_bt(
    const __bf16* __restrict__ Aall, const __bf16* __restrict__ Ball,
    const float* __restrict__ biasAll, __bf16* __restrict__ Call,
    int Ktot, int Ntot, int mtPerE)
{
    __shared__ __bf16 As[128 * 64];
    __shared__ __bf16 Bs[128 * 64];

    const int bn   = blockIdx.x;
    const int bm   = blockIdx.y;
    const int e    = bm / mtPerE;
    const size_t row0 = (size_t)bm * 128;
    const int col0 = bn * 128;

    const __bf16* A  = Aall + row0 * Ktot;
    const __bf16* Bt = Ball + ((size_t)e * Ntot + col0) * (size_t)Ktot;

    const int tid  = threadIdx.x;
    const int wave = tid >> 6, lane = tid & 63;
    const int wr = wave >> 1, wc = wave & 1;
    const int lr = lane & 15;            // fragment row/col
    const int lk = (lane >> 4) * 8;      // fragment k offset

    f32x4 acc[4][4] = {};

    for (int kt = 0; kt < Ktot; kt += 64) {
        __syncthreads();
#pragma unroll
        for (int i = 0; i < 4; ++i) {
            const int c = (wave * 4 + i) * 64 + lane;
            const __bf16* ga = A  + (size_t)(c >> 3) * Ktot + (kt + (c & 7) * 8);
            const __bf16* gb = Bt + (size_t)(c >> 3) * Ktot + (kt + (c & 7) * 8);
            __builtin_amdgcn_global_load_lds(
                (const __attribute__((address_space(1))) void*)ga,
                (__attribute__((address_space(3))) void*)(As + (wave * 4 + i) * 512),
                16, 0, 0);
            __builtin_amdgcn_global_load_lds(
                (const __attribute__((address_space(1))) void*)gb,
                (__attribute__((address_space(3))) void*)(Bs + (wave * 4 + i) * 512),
                16, 0, 0);
        }
        __syncthreads();
#pragma unroll
        for (int kk = 0; kk < 64; kk += 32) {
            bf16x8 af[4], bfr[4];
#pragma unroll
            for (int m = 0; m < 4; ++m)
                af[m] = *(const bf16x8*)&As[(wr * 64 + m * 16 + lr) * 64 + kk + lk];
#pragma unroll
            for (int nn = 0; nn < 4; ++nn)
                bfr[nn] = *(const bf16x8*)&Bs[(wc * 64 + nn * 16 + lr) * 64 + kk + lk];
#pragma unroll
            for (int m = 0; m < 4; ++m)
#pragma unroll
                for (int nn = 0; nn < 4; ++nn)
                    acc[m][nn] = __builtin_amdgcn_mfma_f32_16x16x32_bf16(
                        af[m], bfr[nn], acc[m][nn], 0, 0, 0);
        }
    }

    // Epilogue: C/D layout col = lane&15, row = (lane>>4)*4 + i  [HW-verified]
#pragma unroll
    for (int nn = 0; nn < 4; ++nn) {
        const int col = col0 + wc * 64 + nn * 16 + lr;
        float bias = 0.f;
        if (GELU) bias = biasAll[(size_t)e * Ntot + col];
#pragma unroll
        for (int m = 0; m < 4; ++m) {
#pragma unroll
            for (int i = 0; i < 4; ++i) {
                float v = acc[m][nn][i];
                if (GELU) {
                    v += bias;
                    v = 0.5f * v * (1.0f + erff(v * 0.70710678118654752f));
                }
                const size_t row = row0 + wr * 64 + m * 16 + (lane >> 4) * 4 + i;
                Call[row * Ntot + col] = (__bf16)v;
            }
        }
    }
}

// ---------------------------------------------------------------------------
// Combine: y[n][c] = sum_k gate * (out[slot][c] + b2[e][c]); writes all of y.
// ---------------------------------------------------------------------------
__global__ __launch_bounds__(256) void k_combine(
    const __bf16* __restrict__ outb, const int* __restrict__ slot,
    const float* __restrict__ gates, const int* __restrict__ tidx,
    const float* __restrict__ b2, float* __restrict__ y)
{
    const int n = blockIdx.x;
    const int t = threadIdx.x;
    const int c = t * 4;
    float r0 = 0.f, r1 = 0.f, r2 = 0.f, r3 = 0.f;
#pragma unroll
    for (int k = 0; k < KTOP; ++k) {
        const int s = slot[n * 2 + k];
        if (s < 0) continue;
        const float g = gates[n * 2 + k];
        const int   e = tidx[n * 2 + k];
        const bf16x4 v = *(const bf16x4*)(outb + (size_t)s * CDIM + c);
        const float4 bb = *(const float4*)(b2 + (size_t)e * CDIM + c);
        r0 += g * ((float)v[0] + bb.x);
        r1 += g * ((float)v[1] + bb.y);
        r2 += g * ((float)v[2] + bb.z);
        r3 += g * ((float)v[3] + bb.w);
    }
    float4 o = make_float4(r0, r1, r2, r3);
    *(float4*)(y + (size_t)n * CDIM + c) = o;
}

// ---------------------------------------------------------------------------
extern "C" void kernel_launch(void* const* d_in, const int* in_sizes, int n_in,
                              void* d_out, int out_size, void* d_ws, size_t ws_size,
                              hipStream_t stream)
{
    const float* x  = (const float*)d_in[0];
    const float* rw = (const float*)d_in[1];
    const float* rb = (const float*)d_in[2];
    const float* w1 = (const float*)d_in[3];
    const float* b1 = (const float*)d_in[4];
    const float* w2 = (const float*)d_in[5];
    const float* b2 = (const float*)d_in[6];
    float* y = (float*)d_out;

    char* ws = (char*)d_ws;
    size_t off = 0;
    auto alloc = [&](size_t bytes) -> void* {
        void* p = ws + off;
        off = (off + bytes + 255) & ~(size_t)255;
        return p;
    };
    __bf16* w1t  = (__bf16*)alloc((size_t)NE * CDIM * HDIM * 2);   // [E][H][C]
    __bf16* w2t  = (__bf16*)alloc((size_t)NE * CDIM * HDIM * 2);   // [E][C][H]
    __bf16* inp  = (__bf16*)alloc((size_t)NE * CAPE * CDIM * 2);   // [E*cap][C]
    __bf16* hbuf = (__bf16*)alloc((size_t)NE * CAPE * HDIM * 2);   // [E*cap][H]
    __bf16* outb = (__bf16*)alloc((size_t)NE * CAPE * CDIM * 2);   // [E*cap][C]
    float*  probs = (float*)alloc((size_t)NTOK * NE * 4);
    float*  gates = (float*)alloc((size_t)NTOK * 2 * 4);
    int*    tidx  = (int*)alloc((size_t)NTOK * 2 * 4);
    int*    slot  = (int*)alloc((size_t)NTOK * 2 * 4);
    int*    tok   = (int*)alloc((size_t)NE * CAPE * 4);

    // 1. weight conversion (transposed to B^T layout, bf16)
    k_transpose_bf16<<<dim3(HDIM / 32, CDIM / 32, NE), dim3(32, 8), 0, stream>>>(
        w1, w1t, CDIM, HDIM);
    k_transpose_bf16<<<dim3(CDIM / 32, HDIM / 32, NE), dim3(32, 8), 0, stream>>>(
        w2, w2t, HDIM, CDIM);

    // 2. router (fp32 exact-ish)
    k_router<<<NTOK / 4, 256, 0, stream>>>(x, rw, rb, probs, gates, tidx);

    // 3. dispatch scan + aux loss (single block, exact FCFS order)
    k_scan<<<1, 256, 0, stream>>>(tidx, probs, slot, tok, y + (size_t)NTOK * CDIM);

    // 4. gather expert inputs (bf16)
    k_gather<<<NE * CAPE, 256, 0, stream>>>(x, tok, inp);

    // 5. expert FFN
    k_gemm_bt<true><<<dim3(HDIM / 128, NE * CAPE / 128), 256, 0, stream>>>(
        inp, w1t, b1, hbuf, CDIM, HDIM, CAPE / 128);
    k_gemm_bt<false><<<dim3(CDIM / 128, NE * CAPE / 128), 256, 0, stream>>>(
        hbuf, w2t, nullptr, outb, HDIM, CDIM, CAPE / 128);

    // 6. combine back to tokens (+aux already written)
    k_combine<<<NTOK, 256, 0, stream>>>(outb, slot, gates, tidx, b2, y);
}

// Round 2
// 428.398 us; speedup vs baseline: 1.3414x; 1.3414x over previous
//
#include <hip/hip_runtime.h>
#include <hip/hip_bf16.h>
#include <math.h>

#define NE    8
#define KTOP  2
#define CDIM  1024
#define HDIM  4096
#define NTOK  8192
#define CAPE  1280
#define NSLOT (NTOK * KTOP)

typedef __bf16 bf16x8 __attribute__((ext_vector_type(8)));
typedef __bf16 bf16x4 __attribute__((ext_vector_type(4)));
typedef float  f32x4  __attribute__((ext_vector_type(4)));

// ---------------------------------------------------------------------------
// Transposing fp32 -> bf16 weight conversion: src [E][R][Cc] -> dst [E][Cc][R]
// ---------------------------------------------------------------------------
__global__ __launch_bounds__(256) void k_transpose_bf16(
    const float* __restrict__ src, __bf16* __restrict__ dst, int R, int Cc)
{
    __shared__ float tile[32][33];
    const int e  = blockIdx.z;
    const int cb = blockIdx.x * 32;
    const int rb = blockIdx.y * 32;
    const int tx = threadIdx.x, ty = threadIdx.y;
    const float* s = src + (size_t)e * R * Cc;
    __bf16*      d = dst + (size_t)e * R * Cc;
#pragma unroll
    for (int i = 0; i < 32; i += 8)
        tile[ty + i][tx] = s[(size_t)(rb + ty + i) * Cc + cb + tx];
    __syncthreads();
#pragma unroll
    for (int i = 0; i < 32; i += 8)
        d[(size_t)(cb + ty + i) * R + rb + tx] = (__bf16)tile[tx][ty + i];
}

// ---------------------------------------------------------------------------
// Router: fp32 logits -> softmax -> top2 -> normalized gates. 1 wave = 1 token.
// ---------------------------------------------------------------------------
__global__ __launch_bounds__(256) void k_router(
    const float* __restrict__ x, const float* __restrict__ rw,
    const float* __restrict__ rb, float* __restrict__ probs,
    float* __restrict__ gates, int* __restrict__ tidx)
{
    __shared__ float rws[NE * CDIM];
    const int tid = threadIdx.x;
    for (int i = tid; i < NE * CDIM / 4; i += 256)
        ((float4*)rws)[i] = ((const float4*)rw)[i];
    __syncthreads();

    const int wave = tid >> 6, lane = tid & 63;
    const int n = blockIdx.x * 4 + wave;
    const float* xr = x + (size_t)n * CDIM;

    float acc[NE];
#pragma unroll
    for (int e = 0; e < NE; ++e) acc[e] = 0.f;
    for (int j = 0; j < CDIM / 64; ++j) {
        const float xv = xr[j * 64 + lane];
#pragma unroll
        for (int e = 0; e < NE; ++e) acc[e] += xv * rws[e * CDIM + j * 64 + lane];
    }
#pragma unroll
    for (int off = 32; off > 0; off >>= 1) {
#pragma unroll
        for (int e = 0; e < NE; ++e) acc[e] += __shfl_down(acc[e], off);
    }
    if (lane == 0) {
        float mx = -1e30f;
#pragma unroll
        for (int e = 0; e < NE; ++e) { acc[e] += rb[e]; mx = fmaxf(mx, acc[e]); }
        float p[NE], s = 0.f;
#pragma unroll
        for (int e = 0; e < NE; ++e) { p[e] = expf(acc[e] - mx); s += p[e]; }
        const float inv = 1.f / s;
#pragma unroll
        for (int e = 0; e < NE; ++e) { p[e] *= inv; probs[(size_t)n * NE + e] = p[e]; }
        int   i1 = 0;  float v1 = p[0];
        int   i2 = -1; float v2 = -1.f;
#pragma unroll
        for (int e = 1; e < NE; ++e) {
            if (p[e] > v1)      { v2 = v1; i2 = i1; v1 = p[e]; i1 = e; }
            else if (p[e] > v2) { v2 = p[e]; i2 = e; }
        }
        const float gs = 1.f / (v1 + v2);
        gates[n * 2 + 0] = v1 * gs;  gates[n * 2 + 1] = v2 * gs;
        tidx[n * 2 + 0]  = i1;       tidx[n * 2 + 1]  = i2;
    }
}

// ---------------------------------------------------------------------------
// Single-block scan: exact slot-order ranks, capacity drop, tok_buf, aux loss.
// ---------------------------------------------------------------------------
__global__ __launch_bounds__(256) void k_scan(
    const int* __restrict__ tidx, const float* __restrict__ probs,
    int* __restrict__ slot, int* __restrict__ tok, float* __restrict__ d_aux)
{
    __shared__ int   lcnt[256][NE];
    __shared__ float ps[256][NE];
    const int t = threadIdx.x;

    for (int i = t; i < NE * CAPE; i += 256) tok[i] = 0;

    int c8[NE];
#pragma unroll
    for (int e = 0; e < NE; ++e) c8[e] = 0;
    const int per  = NSLOT / 256;   // 64
    const int base = t * per;
    for (int s = 0; s < per; ++s) c8[tidx[base + s]]++;
#pragma unroll
    for (int e = 0; e < NE; ++e) lcnt[t][e] = c8[e];

    float f8[NE];
#pragma unroll
    for (int e = 0; e < NE; ++e) f8[e] = 0.f;
    for (int n = t; n < NTOK; n += 256) {
        const float4 a = *(const float4*)(probs + (size_t)n * NE);
        const float4 b = *(const float4*)(probs + (size_t)n * NE + 4);
        f8[0] += a.x; f8[1] += a.y; f8[2] += a.z; f8[3] += a.w;
        f8[4] += b.x; f8[5] += b.y; f8[6] += b.z; f8[7] += b.w;
    }
#pragma unroll
    for (int e = 0; e < NE; ++e) ps[t][e] = f8[e];

    __syncthreads();

    int pre[NE], tot[NE];
#pragma unroll
    for (int e = 0; e < NE; ++e) { pre[e] = 0; tot[e] = 0; }
    for (int tt = 0; tt < 256; ++tt) {
#pragma unroll
        for (int e = 0; e < NE; ++e) {
            const int v = lcnt[tt][e];
            tot[e] += v;
            if (tt < t) pre[e] += v;
        }
    }
    for (int s = 0; s < per; ++s) {
        const int sg = base + s;
        const int e  = tidx[sg];
        const int p  = pre[e]++;
        if (p < CAPE) { slot[sg] = e * CAPE + p; tok[e * CAPE + p] = sg >> 1; }
        else          { slot[sg] = -1; }
    }
    if (t == 0) {
        float imp[NE], isum = 0.f, ld[NE], lsum = 0.f;
#pragma unroll
        for (int e = 0; e < NE; ++e) {
            float v = 0.f;
            for (int tt = 0; tt < 256; ++tt) v += ps[tt][e];
            imp[e] = v; isum += v;
        }
#pragma unroll
        for (int e = 0; e < NE; ++e) { ld[e] = fminf((float)tot[e], (float)CAPE); lsum += ld[e]; }
        float aux = 0.f;
#pragma unroll
        for (int e = 0; e < NE; ++e) aux += (imp[e] / isum) * (ld[e] / lsum);
        *d_aux = aux * (float)(NE * NE);
    }
}

// ---------------------------------------------------------------------------
// Gather tokens into dense per-expert buffers, fp32 -> bf16.
// ---------------------------------------------------------------------------
__global__ __launch_bounds__(256) void k_gather(
    const float* __restrict__ x, const int* __restrict__ tok,
    __bf16* __restrict__ inp)
{
    const int row = blockIdx.x;
    const int t   = threadIdx.x;
    const int tk  = tok[row];
    const float4 v = ((const float4*)(x + (size_t)tk * CDIM))[t];
    bf16x4 o;
    o[0] = (__bf16)v.x; o[1] = (__bf16)v.y; o[2] = (__bf16)v.z; o[3] = (__bf16)v.w;
    *(bf16x4*)(inp + (size_t)row * CDIM + t * 4) = o;
}

// ---------------------------------------------------------------------------
// 256x256 8-wave 4-phase MFMA GEMM (T1+T2+T3+T4+T5 stack), B^T per-expert.
//   A [M][K] bf16, Bt [E][N][K] bf16, C [M][N] bf16.
//   LDS 128KiB: [buf 2][op A/B][half 2] of 128x64 bf16, XOR-swizzled
//   (byte ^= (row&7)<<4) via pre-swizzled global source (linear LDS dest).
//   Stage ring: tile T's A halves staged at T-1.p1/p2, B halves at T-2.p3/p4;
//   vmcnt(4) once per tile, never 0 in steady state.
//   MFMA operands swapped (mfma(b,a,acc)) so lane's 4 acc elems are
//   col-contiguous -> bf16x4 stores.
// ---------------------------------------------------------------------------
#define MFMA_BF16 __builtin_amdgcn_mfma_f32_16x16x32_bf16

template <bool GELU>
__global__ __launch_bounds__(512, 2) void k_gemm8(
    const __bf16* __restrict__ Aall, const __bf16* __restrict__ Ball,
    const float* __restrict__ biasAll, __bf16* __restrict__ Call,
    int Ktot, int Ntot, int NBN, int mtPerE)
{
    __shared__ char lds[131072];

    const int NK  = Ktot >> 6;
    const int nwg = gridDim.x;
    const int cpx = nwg >> 3;                       // grid % 8 == 0 by caller
    const int id  = blockIdx.x;
    const int sid = (id & 7) * cpx + (id >> 3);     // bijective XCD swizzle
    const int bm  = sid / NBN, bn = sid % NBN;
    const int e   = bm / mtPerE;

    const size_t row0 = (size_t)bm * 256;
    const int    col0 = bn * 256;

    const __bf16* gA = Aall + row0 * (size_t)Ktot;
    const __bf16* gB = Ball + ((size_t)e * Ntot + col0) * (size_t)Ktot;

    const int tid = threadIdx.x;
    const int w   = tid >> 6, l = tid & 63;
    const int wr  = w >> 2, wc = w & 3;
    const int lr  = l & 15, hi = l >> 4;

    // staging lane constants: lane covers chunk c = i*512 + w*64 + l
    const int srow = (w << 3) + (l >> 3);                  // row (i=0) within 128-row half
    const int kf   = ((l & 7) ^ (l >> 3)) << 3;            // pre-swizzled k elem offset
    // ds_read swizzled k-byte offsets (kk=0 / kk=32)
    const int swz = (l & 7) << 4;
    const int kb0 = (hi << 4) ^ swz;
    const int kb1 = (64 + (hi << 4)) ^ swz;

    auto STAGE = [&](int buf, int op, int half, int kt) {
        const __bf16* g = (op ? gB : gA)
            + (size_t)(half * 128 + srow) * Ktot + kt * 64 + kf;
        char* d = lds + ((((buf << 1) + op) << 1) + half) * 16384 + w * 1024;
        __builtin_amdgcn_global_load_lds(
            (const __attribute__((address_space(1))) void*)g,
            (__attribute__((address_space(3))) void*)d, 16, 0, 0);
        __builtin_amdgcn_global_load_lds(
            (const __attribute__((address_space(1))) void*)(g + (size_t)64 * Ktot),
            (__attribute__((address_space(3))) void*)(d + 8192), 16, 0, 0);
    };

    // ---- prologue: tile0 A+B, tile1 B ----
    STAGE(0, 0, 0, 0); STAGE(0, 0, 1, 0);
    STAGE(0, 1, 0, 0); STAGE(0, 1, 1, 0);
    if (NK > 1) {
        STAGE(1, 1, 0, 1); STAGE(1, 1, 1, 1);
        asm volatile("s_waitcnt vmcnt(4)" ::: "memory");
    } else {
        asm volatile("s_waitcnt vmcnt(0)" ::: "memory");
    }
    __builtin_amdgcn_s_barrier();
    __builtin_amdgcn_sched_barrier(0);

    f32x4 acc[8][4] = {};
    bf16x8 bfr[4][2], a[2][2];

#define PHASE_MFMA(MB)                                                        \
    __builtin_amdgcn_s_barrier();                                             \
    asm volatile("s_waitcnt lgkmcnt(0)" ::: "memory");                        \
    __builtin_amdgcn_sched_barrier(0);                                        \
    __builtin_amdgcn_s_setprio(1);                                            \
    _Pragma("unroll")                                                         \
    for (int mm = 0; mm < 2; ++mm) {                                          \
        _Pragma("unroll")                                                     \
        for (int n = 0; n < 4; ++n) {                                         \
            acc[(MB) + mm][n] = MFMA_BF16(bfr[n][0], a[mm][0], acc[(MB) + mm][n], 0, 0, 0); \
            acc[(MB) + mm][n] = MFMA_BF16(bfr[n][1], a[mm][1], acc[(MB) + mm][n], 0, 0, 0); \
        }                                                                     \
    }                                                                         \
    __builtin_amdgcn_s_setprio(0);                                            \
    __builtin_amdgcn_s_barrier();                                             \
    __builtin_amdgcn_sched_barrier(0);

#define LOAD_A(MB)                                                            \
    _Pragma("unroll")                                                         \
    for (int mm = 0; mm < 2; ++mm) {                                          \
        a[mm][0] = *(const bf16x8*)(Ab + ((MB) + mm) * 2048 + kb0);           \
        a[mm][1] = *(const bf16x8*)(Ab + ((MB) + mm) * 2048 + kb1);           \
    }

#pragma unroll 2
    for (int T = 0; T < NK; ++T) {
        const int cur = T & 1, nxt = cur ^ 1;
        const char* Ab = lds + (((cur << 1) + 0) * 2 + wr) * 16384 + lr * 128;
        const char* Bb = lds + (((cur << 1) + 1) * 2 + (wc >> 1)) * 16384
                             + (wc & 1) * 8192 + lr * 128;

        // ---- phase 1: B frags + A m0,m1 ; stage T+1.A0 ----
#pragma unroll
        for (int n = 0; n < 4; ++n) {
            bfr[n][0] = *(const bf16x8*)(Bb + n * 2048 + kb0);
            bfr[n][1] = *(const bf16x8*)(Bb + n * 2048 + kb1);
        }
        LOAD_A(0)
        if (T + 1 < NK) STAGE(nxt, 0, 0, T + 1);
        PHASE_MFMA(0)

        // ---- phase 2: A m2,m3 ; stage T+1.A1 ----
        LOAD_A(2)
        if (T + 1 < NK) STAGE(nxt, 0, 1, T + 1);
        PHASE_MFMA(2)

        // ---- phase 3: A m4,m5 ; stage T+2.B0 (into cur buf, B reads done p1) ----
        LOAD_A(4)
        if (T + 2 < NK) STAGE(cur, 1, 0, T + 2);
        PHASE_MFMA(4)

        // ---- phase 4: A m6,m7 ; stage T+2.B1 ; counted vmcnt gate ----
        LOAD_A(6)
        if (T + 2 < NK) {
            STAGE(cur, 1, 1, T + 2);
            asm volatile("s_waitcnt vmcnt(4)" ::: "memory");
        } else if (T + 1 < NK) {
            asm volatile("s_waitcnt vmcnt(0)" ::: "memory");
        }
        PHASE_MFMA(6)
    }

    // ---- epilogue: row = m*16 + lr, col = n*16 + hi*4 + i (bf16x4 stores) ----
    const size_t crow0 = row0 + (size_t)wr * 128;
    const int    ccol0 = col0 + wc * 64;
#pragma unroll
    for (int n = 0; n < 4; ++n) {
        float bb[4] = {0.f, 0.f, 0.f, 0.f};
        if (GELU) {
            const float4 b4 = *(const float4*)(biasAll + (size_t)e * Ntot
                                               + ccol0 + n * 16 + hi * 4);
            bb[0] = b4.x; bb[1] = b4.y; bb[2] = b4.z; bb[3] = b4.w;
        }
#pragma unroll
        for (int m = 0; m < 8; ++m) {
            const f32x4 v = acc[m][n];
            bf16x4 o;
#pragma unroll
            for (int i = 0; i < 4; ++i) {
                float t = v[i];
                if (GELU) {
                    t += bb[i];
                    const float u  = 0.7978845608028654f * (t + 0.044715f * t * t * t);
                    const float ex = __expf(2.f * u);
                    t = t * (1.f - 1.f / (ex + 1.f));   // 0.5t(1+tanh u)
                }
                o[i] = (__bf16)t;
            }
            *(bf16x4*)(Call + (crow0 + m * 16 + lr) * (size_t)Ntot
                       + ccol0 + n * 16 + hi * 4) = o;
        }
    }
}

// ---------------------------------------------------------------------------
// Combine: y[n][c] = sum_k gate * (out[slot][c] + b2[e][c]); writes all of y.
// ---------------------------------------------------------------------------
__global__ __launch_bounds__(256) void k_combine(
    const __bf16* __restrict__ outb, const int* __restrict__ slot,
    const float* __restrict__ gates, const int* __restrict__ tidx,
    const float* __restrict__ b2, float* __restrict__ y)
{
    const int n = blockIdx.x;
    const int t = threadIdx.x;
    const int c = t * 4;
    float r0 = 0.f, r1 = 0.f, r2 = 0.f, r3 = 0.f;
#pragma unroll
    for (int k = 0; k < KTOP; ++k) {
        const int s = slot[n * 2 + k];
        if (s < 0) continue;
        const float g = gates[n * 2 + k];
        const int   e = tidx[n * 2 + k];
        const bf16x4 v = *(const bf16x4*)(outb + (size_t)s * CDIM + c);
        const float4 bb = *(const float4*)(b2 + (size_t)e * CDIM + c);
        r0 += g * ((float)v[0] + bb.x);
        r1 += g * ((float)v[1] + bb.y);
        r2 += g * ((float)v[2] + bb.z);
        r3 += g * ((float)v[3] + bb.w);
    }
    float4 o = make_float4(r0, r1, r2, r3);
    *(float4*)(y + (size_t)n * CDIM + c) = o;
}

// ---------------------------------------------------------------------------
extern "C" void kernel_launch(void* const* d_in, const int* in_sizes, int n_in,
                              void* d_out, int out_size, void* d_ws, size_t ws_size,
                              hipStream_t stream)
{
    const float* x  = (const float*)d_in[0];
    const float* rw = (const float*)d_in[1];
    const float* rb = (const float*)d_in[2];
    const float* w1 = (const float*)d_in[3];
    const float* b1 = (const float*)d_in[4];
    const float* w2 = (const float*)d_in[5];
    const float* b2 = (const float*)d_in[6];
    float* y = (float*)d_out;

    char* ws = (char*)d_ws;
    size_t off = 0;
    auto alloc = [&](size_t bytes) -> void* {
        void* p = ws + off;
        off = (off + bytes + 255) & ~(size_t)255;
        return p;
    };
    __bf16* w1t  = (__bf16*)alloc((size_t)NE * CDIM * HDIM * 2);   // [E][H][C]
    __bf16* w2t  = (__bf16*)alloc((size_t)NE * CDIM * HDIM * 2);   // [E][C][H]
    __bf16* inp  = (__bf16*)alloc((size_t)NE * CAPE * CDIM * 2);   // [E*cap][C]
    __bf16* hbuf = (__bf16*)alloc((size_t)NE * CAPE * HDIM * 2);   // [E*cap][H]
    __bf16* outb = (__bf16*)alloc((size_t)NE * CAPE * CDIM * 2);   // [E*cap][C]
    float*  probs = (float*)alloc((size_t)NTOK * NE * 4);
    float*  gates = (float*)alloc((size_t)NTOK * 2 * 4);
    int*    tidx  = (int*)alloc((size_t)NTOK * 2 * 4);
    int*    slot  = (int*)alloc((size_t)NTOK * 2 * 4);
    int*    tok   = (int*)alloc((size_t)NE * CAPE * 4);

    // 1. weight conversion (transposed to B^T layout, bf16)
    k_transpose_bf16<<<dim3(HDIM / 32, CDIM / 32, NE), dim3(32, 8), 0, stream>>>(
        w1, w1t, CDIM, HDIM);
    k_transpose_bf16<<<dim3(CDIM / 32, HDIM / 32, NE), dim3(32, 8), 0, stream>>>(
        w2, w2t, HDIM, CDIM);

    // 2. router
    k_router<<<NTOK / 4, 256, 0, stream>>>(x, rw, rb, probs, gates, tidx);

    // 3. dispatch scan + aux loss (single block, exact FCFS order)
    k_scan<<<1, 256, 0, stream>>>(tidx, probs, slot, tok, y + (size_t)NTOK * CDIM);

    // 4. gather expert inputs (bf16)
    k_gather<<<NE * CAPE, 256, 0, stream>>>(x, tok, inp);

    // 5. expert FFN — 256^2 8-wave pipelined MFMA GEMMs
    k_gemm8<true><<<dim3((HDIM / 256) * (NE * CAPE / 256)), 512, 0, stream>>>(
        inp, w1t, b1, hbuf, CDIM, HDIM, HDIM / 256, CAPE / 256);
    k_gemm8<false><<<dim3((CDIM / 256) * (NE * CAPE / 256)), 512, 0, stream>>>(
        hbuf, w2t, nullptr, outb, HDIM, CDIM, CDIM / 256, CAPE / 256);

    // 6. combine back to tokens (+aux already written by scan)
    k_combine<<<NTOK, 256, 0, stream>>>(outb, slot, gates, tidx, b2, y);
}

// Round 3
// 427.572 us; speedup vs baseline: 1.3440x; 1.0019x over previous
//
#include <hip/hip_runtime.h>
#include <hip/hip_bf16.h>
#include <math.h>

#define NE    8
#define KTOP  2
#define CDIM  1024
#define HDIM  4096
#define NTOK  8192
#define CAPE  1280
#define NSLOT (NTOK * KTOP)

typedef __bf16 bf16x8 __attribute__((ext_vector_type(8)));
typedef __bf16 bf16x4 __attribute__((ext_vector_type(4)));
typedef __bf16 bf16x2 __attribute__((ext_vector_type(2)));
typedef float  f32x4  __attribute__((ext_vector_type(4)));

#define GAS __attribute__((address_space(1)))
#define LAS __attribute__((address_space(3)))

// ---------------------------------------------------------------------------
// Transposing fp32 -> bf16 weight conversion: src [E][R][Cc] -> dst [E][Cc][R]
// Paired bf16x2 stores (4B/lane).
// ---------------------------------------------------------------------------
__global__ __launch_bounds__(256) void k_transpose_bf16(
    const float* __restrict__ src, __bf16* __restrict__ dst, int R, int Cc)
{
    __shared__ float tile[32][33];
    const int e  = blockIdx.z;
    const int cb = blockIdx.x * 32;
    const int rb = blockIdx.y * 32;
    const int t  = threadIdx.x;
    const int tx = t & 31, ty = t >> 5;
    const float* s = src + (size_t)e * R * Cc;
    __bf16*      d = dst + (size_t)e * R * Cc;
#pragma unroll
    for (int i = 0; i < 32; i += 8)
        tile[ty + i][tx] = s[(size_t)(rb + ty + i) * Cc + cb + tx];
    __syncthreads();
    const int op  = t & 15;      // src-row pair
    const int oc0 = t >> 4;      // out-row base (0..15)
#pragma unroll
    for (int j = 0; j < 2; ++j) {
        const int oc = oc0 + j * 16;
        bf16x2 v;
        v[0] = (__bf16)tile[op * 2][oc];
        v[1] = (__bf16)tile[op * 2 + 1][oc];
        *(bf16x2*)(d + (size_t)(cb + oc) * R + rb + op * 2) = v;
    }
}

// ---------------------------------------------------------------------------
// Router: fp32 logits -> softmax -> top2 -> normalized gates. 1 wave = 1 token.
// ---------------------------------------------------------------------------
__global__ __launch_bounds__(256) void k_router(
    const float* __restrict__ x, const float* __restrict__ rw,
    const float* __restrict__ rb, float* __restrict__ probs,
    float* __restrict__ gates, int* __restrict__ tidx)
{
    __shared__ float rws[NE * CDIM];
    const int tid = threadIdx.x;
    for (int i = tid; i < NE * CDIM / 4; i += 256)
        ((float4*)rws)[i] = ((const float4*)rw)[i];
    __syncthreads();

    const int wave = tid >> 6, lane = tid & 63;
    const int n = blockIdx.x * 4 + wave;
    const float* xr = x + (size_t)n * CDIM;

    float acc[NE];
#pragma unroll
    for (int e = 0; e < NE; ++e) acc[e] = 0.f;
    for (int j = 0; j < CDIM / 64; ++j) {
        const float xv = xr[j * 64 + lane];
#pragma unroll
        for (int e = 0; e < NE; ++e) acc[e] += xv * rws[e * CDIM + j * 64 + lane];
    }
#pragma unroll
    for (int off = 32; off > 0; off >>= 1) {
#pragma unroll
        for (int e = 0; e < NE; ++e) acc[e] += __shfl_down(acc[e], off);
    }
    if (lane == 0) {
        float mx = -1e30f;
#pragma unroll
        for (int e = 0; e < NE; ++e) { acc[e] += rb[e]; mx = fmaxf(mx, acc[e]); }
        float p[NE], s = 0.f;
#pragma unroll
        for (int e = 0; e < NE; ++e) { p[e] = expf(acc[e] - mx); s += p[e]; }
        const float inv = 1.f / s;
#pragma unroll
        for (int e = 0; e < NE; ++e) { p[e] *= inv; probs[(size_t)n * NE + e] = p[e]; }
        int   i1 = 0;  float v1 = p[0];
        int   i2 = -1; float v2 = -1.f;
#pragma unroll
        for (int e = 1; e < NE; ++e) {
            if (p[e] > v1)      { v2 = v1; i2 = i1; v1 = p[e]; i1 = e; }
            else if (p[e] > v2) { v2 = p[e]; i2 = e; }
        }
        const float gs = 1.f / (v1 + v2);
        gates[n * 2 + 0] = v1 * gs;  gates[n * 2 + 1] = v2 * gs;
        tidx[n * 2 + 0]  = i1;       tidx[n * 2 + 1]  = i2;
    }
}

// ---------------------------------------------------------------------------
// Single-block scan: exact slot-order ranks, capacity drop, tok_buf, aux loss.
// ---------------------------------------------------------------------------
__global__ __launch_bounds__(256) void k_scan(
    const int* __restrict__ tidx, const float* __restrict__ probs,
    int* __restrict__ slot, int* __restrict__ tok, float* __restrict__ d_aux)
{
    __shared__ int   lcnt[256][NE];
    __shared__ float ps[256][NE];
    const int t = threadIdx.x;

    for (int i = t; i < NE * CAPE; i += 256) tok[i] = 0;

    int c8[NE];
#pragma unroll
    for (int e = 0; e < NE; ++e) c8[e] = 0;
    const int per  = NSLOT / 256;   // 64
    const int base = t * per;
    for (int s = 0; s < per; ++s) c8[tidx[base + s]]++;
#pragma unroll
    for (int e = 0; e < NE; ++e) lcnt[t][e] = c8[e];

    float f8[NE];
#pragma unroll
    for (int e = 0; e < NE; ++e) f8[e] = 0.f;
    for (int n = t; n < NTOK; n += 256) {
        const float4 a = *(const float4*)(probs + (size_t)n * NE);
        const float4 b = *(const float4*)(probs + (size_t)n * NE + 4);
        f8[0] += a.x; f8[1] += a.y; f8[2] += a.z; f8[3] += a.w;
        f8[4] += b.x; f8[5] += b.y; f8[6] += b.z; f8[7] += b.w;
    }
#pragma unroll
    for (int e = 0; e < NE; ++e) ps[t][e] = f8[e];

    __syncthreads();

    int pre[NE], tot[NE];
#pragma unroll
    for (int e = 0; e < NE; ++e) { pre[e] = 0; tot[e] = 0; }
    for (int tt = 0; tt < 256; ++tt) {
#pragma unroll
        for (int e = 0; e < NE; ++e) {
            const int v = lcnt[tt][e];
            tot[e] += v;
            if (tt < t) pre[e] += v;
        }
    }
    for (int s = 0; s < per; ++s) {
        const int sg = base + s;
        const int e  = tidx[sg];
        const int p  = pre[e]++;
        if (p < CAPE) { slot[sg] = e * CAPE + p; tok[e * CAPE + p] = sg >> 1; }
        else          { slot[sg] = -1; }
    }
    if (t == 0) {
        float imp[NE], isum = 0.f, ld[NE], lsum = 0.f;
#pragma unroll
        for (int e = 0; e < NE; ++e) {
            float v = 0.f;
            for (int tt = 0; tt < 256; ++tt) v += ps[tt][e];
            imp[e] = v; isum += v;
        }
#pragma unroll
        for (int e = 0; e < NE; ++e) { ld[e] = fminf((float)tot[e], (float)CAPE); lsum += ld[e]; }
        float aux = 0.f;
#pragma unroll
        for (int e = 0; e < NE; ++e) aux += (imp[e] / isum) * (ld[e] / lsum);
        *d_aux = aux * (float)(NE * NE);
    }
}

// ---------------------------------------------------------------------------
// Gather tokens into dense per-expert buffers, fp32 -> bf16.
// ---------------------------------------------------------------------------
__global__ __launch_bounds__(256) void k_gather(
    const float* __restrict__ x, const int* __restrict__ tok,
    __bf16* __restrict__ inp)
{
    const int row = blockIdx.x;
    const int t   = threadIdx.x;
    const int tk  = tok[row];
    const float4 v = ((const float4*)(x + (size_t)tk * CDIM))[t];
    bf16x4 o;
    o[0] = (__bf16)v.x; o[1] = (__bf16)v.y; o[2] = (__bf16)v.z; o[3] = (__bf16)v.w;
    *(bf16x4*)(inp + (size_t)row * CDIM + t * 4) = o;
}

// ---------------------------------------------------------------------------
// 256x256 8-wave MFMA GEMM with counted-lgkmcnt LDS/MFMA overlap.
//   Per K-tile: 1 barrier. Issue B frags (8 asm ds_read_b128) + A-pair ping-
//   pong (aX/aY), STAGE all 8 global_load_lds for T+1 into the other buffer,
//   gate each 16-MFMA cluster with lgkmcnt(4) so LDS service overlaps MFMA.
//   vmcnt(0) once per tile (T+1 loads, ~1 tile of latency slack).
//   XOR-swizzled LDS (byte ^= (row&7)<<4) via pre-swizzled global source.
// ---------------------------------------------------------------------------
#define MFMA_BF16 __builtin_amdgcn_mfma_f32_16x16x32_bf16
#define DSR(dst, addr, IMM) \
    asm volatile("ds_read_b128 %0, %1 offset:" #IMM : "=v"(dst) : "v"(addr))
#define WLG(N)  asm volatile("s_waitcnt lgkmcnt(" #N ")" ::: "memory")
#define WVM0()  asm volatile("s_waitcnt vmcnt(0)" ::: "memory")
#define SB0()   __builtin_amdgcn_sched_barrier(0)

#define MFMA_PHASE(MB, AR)                                                    \
    __builtin_amdgcn_s_setprio(1);                                            \
    _Pragma("unroll")                                                         \
    for (int mm = 0; mm < 2; ++mm) {                                          \
        _Pragma("unroll")                                                     \
        for (int n = 0; n < 4; ++n) {                                         \
            acc[(MB) + mm][n] = MFMA_BF16(bfr[n][0], AR[mm][0], acc[(MB) + mm][n], 0, 0, 0); \
            acc[(MB) + mm][n] = MFMA_BF16(bfr[n][1], AR[mm][1], acc[(MB) + mm][n], 0, 0, 0); \
        }                                                                     \
    }                                                                         \
    __builtin_amdgcn_s_setprio(0);                                            \
    SB0();

template <bool GELU>
__global__ __launch_bounds__(512, 2) void k_gemm8(
    const __bf16* __restrict__ Aall, const __bf16* __restrict__ Ball,
    const float* __restrict__ biasAll, __bf16* __restrict__ Call,
    int Ktot, int Ntot, int NBN, int mtPerE)
{
    __shared__ char lds[131072];

    const int NK  = Ktot >> 6;
    const int cpx = gridDim.x >> 3;                 // grid % 8 == 0 by caller
    const int id  = blockIdx.x;
    const int sid = (id & 7) * cpx + (id >> 3);     // bijective XCD swizzle
    const int bm  = sid / NBN, bn = sid % NBN;
    const int e   = bm / mtPerE;

    const size_t row0 = (size_t)bm * 256;
    const int    col0 = bn * 256;

    const int tid = threadIdx.x;
    const int w   = tid >> 6, l = tid & 63;
    const int wr  = w >> 2, wc = w & 3;
    const int lr  = l & 15, hi = l >> 4;

    // ---- staging constants ----
    const int srow = (w << 3) + (l >> 3);                  // 0..63
    const int kf   = ((l & 7) ^ (l >> 3)) << 3;            // pre-swizzled k elems
    const __bf16* pA = Aall + (row0 + srow) * (size_t)Ktot + kf;
    const __bf16* pB = Ball + ((size_t)e * Ntot + col0 + srow) * (size_t)Ktot + kf;
    const size_t rstep = (size_t)64 * Ktot;
    const unsigned L0  = (unsigned)(size_t)(LAS char*)lds;
    const unsigned dA0 = L0 + w * 1024;
    const unsigned dB0 = L0 + 32768 + w * 1024;

    auto STAGE_ALL = [&](unsigned bufbit, int kt) {
        const __bf16* ga = pA + (size_t)kt * 64;
        const __bf16* gb = pB + (size_t)kt * 64;
#pragma unroll
        for (int h = 0; h < 4; ++h)
            __builtin_amdgcn_global_load_lds(
                (const GAS void*)(ga + h * rstep),
                (LAS void*)(size_t)(dA0 + bufbit + h * 8192), 16, 0, 0);
#pragma unroll
        for (int h = 0; h < 4; ++h)
            __builtin_amdgcn_global_load_lds(
                (const GAS void*)(gb + h * rstep),
                (LAS void*)(size_t)(dB0 + bufbit + h * 8192), 16, 0, 0);
    };

    // ---- ds_read lane constants (swizzled) ----
    const unsigned swz = (l & 7) << 4;
    const unsigned kb0 = ((unsigned)(hi << 4)) ^ swz;
    const unsigned kb1 = ((unsigned)(64 + (hi << 4))) ^ swz;
    const unsigned Abase = L0 + wr * 16384 + lr * 128;
    const unsigned Bbase = L0 + 32768 + (wc >> 1) * 16384 + (wc & 1) * 8192 + lr * 128;

    // ---- prologue: stage tile 0 into buf 0 ----
    STAGE_ALL(0, 0);
    WVM0();
    __builtin_amdgcn_s_barrier();
    SB0();

    f32x4 acc[8][4] = {};
    bf16x8 bfr[4][2], aX[2][2], aY[2][2];

    unsigned cb = 0;
    for (int T = 0; T < NK; ++T) {
        const unsigned nb = cb ^ 65536u;
        const unsigned va0 = Abase + cb + kb0, va1 = Abase + cb + kb1;
        const unsigned vb0 = Bbase + cb + kb0, vb1 = Bbase + cb + kb1;

        // B frags + A m0,m1
        DSR(bfr[0][0], vb0, 0);    DSR(bfr[0][1], vb1, 0);
        DSR(bfr[1][0], vb0, 2048); DSR(bfr[1][1], vb1, 2048);
        DSR(bfr[2][0], vb0, 4096); DSR(bfr[2][1], vb1, 4096);
        DSR(bfr[3][0], vb0, 6144); DSR(bfr[3][1], vb1, 6144);
        DSR(aX[0][0], va0, 0);     DSR(aX[0][1], va1, 0);
        DSR(aX[1][0], va0, 2048);  DSR(aX[1][1], va1, 2048);

        // prefetch tile T+1 into the other buffer (readers done pre-barrier)
        if (T + 1 < NK) STAGE_ALL(nb, T + 1);

        // A m2,m3
        DSR(aY[0][0], va0, 4096);  DSR(aY[0][1], va1, 4096);
        DSR(aY[1][0], va0, 6144);  DSR(aY[1][1], va1, 6144);

        WLG(4); SB0();            // B + aX ready; aY in flight
        MFMA_PHASE(0, aX)
        DSR(aX[0][0], va0, 8192);  DSR(aX[0][1], va1, 8192);
        DSR(aX[1][0], va0, 10240); DSR(aX[1][1], va1, 10240);
        WLG(4); SB0();            // aY ready; m4,m5 in flight
        MFMA_PHASE(2, aY)
        DSR(aY[0][0], va0, 12288); DSR(aY[0][1], va1, 12288);
        DSR(aY[1][0], va0, 14336); DSR(aY[1][1], va1, 14336);
        WLG(4); SB0();            // m4,m5 ready; m6,m7 in flight
        MFMA_PHASE(4, aX)
        WLG(0); SB0();
        MFMA_PHASE(6, aY)

        WVM0();                   // T+1 loads landed (issued ~1 tile ago)
        __builtin_amdgcn_s_barrier();
        SB0();
        cb = nb;
    }

    // ---- epilogue: row = m*16 + lr, col = n*16 + hi*4 + i (bf16x4 stores) ----
    const size_t crow0 = row0 + (size_t)wr * 128;
    const int    ccol0 = col0 + wc * 64;
#pragma unroll
    for (int n = 0; n < 4; ++n) {
        float bb[4] = {0.f, 0.f, 0.f, 0.f};
        if (GELU) {
            const float4 b4 = *(const float4*)(biasAll + (size_t)e * Ntot
                                               + ccol0 + n * 16 + hi * 4);
            bb[0] = b4.x; bb[1] = b4.y; bb[2] = b4.z; bb[3] = b4.w;
        }
#pragma unroll
        for (int m = 0; m < 8; ++m) {
            const f32x4 v = acc[m][n];
            bf16x4 o;
#pragma unroll
            for (int i = 0; i < 4; ++i) {
                float t = v[i];
                if (GELU) {
                    t += bb[i];
                    const float u  = 0.7978845608028654f * (t + 0.044715f * t * t * t);
                    const float ex = __expf(2.f * u);
                    t = t * (1.f - 1.f / (ex + 1.f));   // 0.5t(1+tanh u)
                }
                o[i] = (__bf16)t;
            }
            *(bf16x4*)(Call + (crow0 + m * 16 + lr) * (size_t)Ntot
                       + ccol0 + n * 16 + hi * 4) = o;
        }
    }
}

// ---------------------------------------------------------------------------
// Combine: y[n][c] = sum_k gate * (out[slot][c] + b2[e][c]); writes all of y.
// ---------------------------------------------------------------------------
__global__ __launch_bounds__(256) void k_combine(
    const __bf16* __restrict__ outb, const int* __restrict__ slot,
    const float* __restrict__ gates, const int* __restrict__ tidx,
    const float* __restrict__ b2, float* __restrict__ y)
{
    const int n = blockIdx.x;
    const int t = threadIdx.x;
    const int c = t * 4;
    float r0 = 0.f, r1 = 0.f, r2 = 0.f, r3 = 0.f;
#pragma unroll
    for (int k = 0; k < KTOP; ++k) {
        const int s = slot[n * 2 + k];
        if (s < 0) continue;
        const float g = gates[n * 2 + k];
        const int   e = tidx[n * 2 + k];
        const bf16x4 v = *(const bf16x4*)(outb + (size_t)s * CDIM + c);
        const float4 bb = *(const float4*)(b2 + (size_t)e * CDIM + c);
        r0 += g * ((float)v[0] + bb.x);
        r1 += g * ((float)v[1] + bb.y);
        r2 += g * ((float)v[2] + bb.z);
        r3 += g * ((float)v[3] + bb.w);
    }
    float4 o = make_float4(r0, r1, r2, r3);
    *(float4*)(y + (size_t)n * CDIM + c) = o;
}

// ---------------------------------------------------------------------------
extern "C" void kernel_launch(void* const* d_in, const int* in_sizes, int n_in,
                              void* d_out, int out_size, void* d_ws, size_t ws_size,
                              hipStream_t stream)
{
    const float* x  = (const float*)d_in[0];
    const float* rw = (const float*)d_in[1];
    const float* rb = (const float*)d_in[2];
    const float* w1 = (const float*)d_in[3];
    const float* b1 = (const float*)d_in[4];
    const float* w2 = (const float*)d_in[5];
    const float* b2 = (const float*)d_in[6];
    float* y = (float*)d_out;

    char* ws = (char*)d_ws;
    size_t off = 0;
    auto alloc = [&](size_t bytes) -> void* {
        void* p = ws + off;
        off = (off + bytes + 255) & ~(size_t)255;
        return p;
    };
    __bf16* w1t  = (__bf16*)alloc((size_t)NE * CDIM * HDIM * 2);   // [E][H][C]
    __bf16* w2t  = (__bf16*)alloc((size_t)NE * CDIM * HDIM * 2);   // [E][C][H]
    __bf16* inp  = (__bf16*)alloc((size_t)NE * CAPE * CDIM * 2);   // [E*cap][C]
    __bf16* hbuf = (__bf16*)alloc((size_t)NE * CAPE * HDIM * 2);   // [E*cap][H]
    __bf16* outb = (__bf16*)alloc((size_t)NE * CAPE * CDIM * 2);   // [E*cap][C]
    float*  probs = (float*)alloc((size_t)NTOK * NE * 4);
    float*  gates = (float*)alloc((size_t)NTOK * 2 * 4);
    int*    tidx  = (int*)alloc((size_t)NTOK * 2 * 4);
    int*    slot  = (int*)alloc((size_t)NTOK * 2 * 4);
    int*    tok   = (int*)alloc((size_t)NE * CAPE * 4);

    // 1. weight conversion (transposed to B^T layout, bf16)
    k_transpose_bf16<<<dim3(HDIM / 32, CDIM / 32, NE), 256, 0, stream>>>(
        w1, w1t, CDIM, HDIM);
    k_transpose_bf16<<<dim3(CDIM / 32, HDIM / 32, NE), 256, 0, stream>>>(
        w2, w2t, HDIM, CDIM);

    // 2. router
    k_router<<<NTOK / 4, 256, 0, stream>>>(x, rw, rb, probs, gates, tidx);

    // 3. dispatch scan + aux loss (single block, exact FCFS order)
    k_scan<<<1, 256, 0, stream>>>(tidx, probs, slot, tok, y + (size_t)NTOK * CDIM);

    // 4. gather expert inputs (bf16)
    k_gather<<<NE * CAPE, 256, 0, stream>>>(x, tok, inp);

    // 5. expert FFN — 256^2 8-wave pipelined MFMA GEMMs
    k_gemm8<true><<<dim3((HDIM / 256) * (NE * CAPE / 256)), 512, 0, stream>>>(
        inp, w1t, b1, hbuf, CDIM, HDIM, HDIM / 256, CAPE / 256);
    k_gemm8<false><<<dim3((CDIM / 256) * (NE * CAPE / 256)), 512, 0, stream>>>(
        hbuf, w2t, nullptr, outb, HDIM, CDIM, CDIM / 256, CAPE / 256);

    // 6. combine back to tokens (+aux already written by scan)
    k_combine<<<NTOK, 256, 0, stream>>>(outb, slot, gates, tidx, b2, y);
}

// Round 4
// 407.337 us; speedup vs baseline: 1.4108x; 1.0497x over previous
//
#include <hip/hip_runtime.h>
#include <hip/hip_bf16.h>
#include <math.h>

#define NE    8
#define KTOP  2
#define CDIM  1024
#define HDIM  4096
#define NTOK  8192
#define CAPE  1280
#define NSLOT (NTOK * KTOP)

typedef __bf16 bf16x8 __attribute__((ext_vector_type(8)));
typedef __bf16 bf16x4 __attribute__((ext_vector_type(4)));
typedef __bf16 bf16x2 __attribute__((ext_vector_type(2)));
typedef float  f32x4  __attribute__((ext_vector_type(4)));

#define GAS __attribute__((address_space(1)))
#define LAS __attribute__((address_space(3)))

// ---------------------------------------------------------------------------
// Transposing fp32 -> bf16 weight conversion: src [E][R][Cc] -> dst [E][Cc][R]
// ---------------------------------------------------------------------------
__global__ __launch_bounds__(256) void k_transpose_bf16(
    const float* __restrict__ src, __bf16* __restrict__ dst, int R, int Cc)
{
    __shared__ float tile[32][33];
    const int e  = blockIdx.z;
    const int cb = blockIdx.x * 32;
    const int rb = blockIdx.y * 32;
    const int t  = threadIdx.x;
    const int tx = t & 31, ty = t >> 5;
    const float* s = src + (size_t)e * R * Cc;
    __bf16*      d = dst + (size_t)e * R * Cc;
#pragma unroll
    for (int i = 0; i < 32; i += 8)
        tile[ty + i][tx] = s[(size_t)(rb + ty + i) * Cc + cb + tx];
    __syncthreads();
    const int op  = t & 15;      // src-row pair
    const int oc0 = t >> 4;      // out-row base (0..15)
#pragma unroll
    for (int j = 0; j < 2; ++j) {
        const int oc = oc0 + j * 16;
        bf16x2 v;
        v[0] = (__bf16)tile[op * 2][oc];
        v[1] = (__bf16)tile[op * 2 + 1][oc];
        *(bf16x2*)(d + (size_t)(cb + oc) * R + rb + op * 2) = v;
    }
}

// ---------------------------------------------------------------------------
// Router: fp32 logits -> softmax -> top2 -> normalized gates. 1 wave = 1 token.
// ---------------------------------------------------------------------------
__global__ __launch_bounds__(256) void k_router(
    const float* __restrict__ x, const float* __restrict__ rw,
    const float* __restrict__ rb, float* __restrict__ probs,
    float* __restrict__ gates, int* __restrict__ tidx)
{
    __shared__ float rws[NE * CDIM];
    const int tid = threadIdx.x;
    for (int i = tid; i < NE * CDIM / 4; i += 256)
        ((float4*)rws)[i] = ((const float4*)rw)[i];
    __syncthreads();

    const int wave = tid >> 6, lane = tid & 63;
    const int n = blockIdx.x * 4 + wave;
    const float* xr = x + (size_t)n * CDIM;

    float acc[NE];
#pragma unroll
    for (int e = 0; e < NE; ++e) acc[e] = 0.f;
    for (int j = 0; j < CDIM / 64; ++j) {
        const float xv = xr[j * 64 + lane];
#pragma unroll
        for (int e = 0; e < NE; ++e) acc[e] += xv * rws[e * CDIM + j * 64 + lane];
    }
#pragma unroll
    for (int off = 32; off > 0; off >>= 1) {
#pragma unroll
        for (int e = 0; e < NE; ++e) acc[e] += __shfl_down(acc[e], off);
    }
    if (lane == 0) {
        float mx = -1e30f;
#pragma unroll
        for (int e = 0; e < NE; ++e) { acc[e] += rb[e]; mx = fmaxf(mx, acc[e]); }
        float p[NE], s = 0.f;
#pragma unroll
        for (int e = 0; e < NE; ++e) { p[e] = expf(acc[e] - mx); s += p[e]; }
        const float inv = 1.f / s;
#pragma unroll
        for (int e = 0; e < NE; ++e) { p[e] *= inv; probs[(size_t)n * NE + e] = p[e]; }
        int   i1 = 0;  float v1 = p[0];
        int   i2 = -1; float v2 = -1.f;
#pragma unroll
        for (int e = 1; e < NE; ++e) {
            if (p[e] > v1)      { v2 = v1; i2 = i1; v1 = p[e]; i1 = e; }
            else if (p[e] > v2) { v2 = p[e]; i2 = e; }
        }
        const float gs = 1.f / (v1 + v2);
        gates[n * 2 + 0] = v1 * gs;  gates[n * 2 + 1] = v2 * gs;
        tidx[n * 2 + 0]  = i1;       tidx[n * 2 + 1]  = i2;
    }
}

// ---------------------------------------------------------------------------
// Single-block scan: exact slot-order ranks, capacity drop, tok_buf, aux loss.
// ---------------------------------------------------------------------------
__global__ __launch_bounds__(256) void k_scan(
    const int* __restrict__ tidx, const float* __restrict__ probs,
    int* __restrict__ slot, int* __restrict__ tok, float* __restrict__ d_aux)
{
    __shared__ int   lcnt[256][NE];
    __shared__ float ps[256][NE];
    const int t = threadIdx.x;

    for (int i = t; i < NE * CAPE; i += 256) tok[i] = 0;

    int c8[NE];
#pragma unroll
    for (int e = 0; e < NE; ++e) c8[e] = 0;
    const int per  = NSLOT / 256;   // 64
    const int base = t * per;
    for (int s = 0; s < per; ++s) c8[tidx[base + s]]++;
#pragma unroll
    for (int e = 0; e < NE; ++e) lcnt[t][e] = c8[e];

    float f8[NE];
#pragma unroll
    for (int e = 0; e < NE; ++e) f8[e] = 0.f;
    for (int n = t; n < NTOK; n += 256) {
        const float4 a = *(const float4*)(probs + (size_t)n * NE);
        const float4 b = *(const float4*)(probs + (size_t)n * NE + 4);
        f8[0] += a.x; f8[1] += a.y; f8[2] += a.z; f8[3] += a.w;
        f8[4] += b.x; f8[5] += b.y; f8[6] += b.z; f8[7] += b.w;
    }
#pragma unroll
    for (int e = 0; e < NE; ++e) ps[t][e] = f8[e];

    __syncthreads();

    int pre[NE], tot[NE];
#pragma unroll
    for (int e = 0; e < NE; ++e) { pre[e] = 0; tot[e] = 0; }
    for (int tt = 0; tt < 256; ++tt) {
#pragma unroll
        for (int e = 0; e < NE; ++e) {
            const int v = lcnt[tt][e];
            tot[e] += v;
            if (tt < t) pre[e] += v;
        }
    }
    for (int s = 0; s < per; ++s) {
        const int sg = base + s;
        const int e  = tidx[sg];
        const int p  = pre[e]++;
        if (p < CAPE) { slot[sg] = e * CAPE + p; tok[e * CAPE + p] = sg >> 1; }
        else          { slot[sg] = -1; }
    }
    if (t == 0) {
        float imp[NE], isum = 0.f, ld[NE], lsum = 0.f;
#pragma unroll
        for (int e = 0; e < NE; ++e) {
            float v = 0.f;
            for (int tt = 0; tt < 256; ++tt) v += ps[tt][e];
            imp[e] = v; isum += v;
        }
#pragma unroll
        for (int e = 0; e < NE; ++e) { ld[e] = fminf((float)tot[e], (float)CAPE); lsum += ld[e]; }
        float aux = 0.f;
#pragma unroll
        for (int e = 0; e < NE; ++e) aux += (imp[e] / isum) * (ld[e] / lsum);
        *d_aux = aux * (float)(NE * NE);
    }
}

// ---------------------------------------------------------------------------
// Gather tokens into dense per-expert buffers, fp32 -> bf16.
// ---------------------------------------------------------------------------
__global__ __launch_bounds__(256) void k_gather(
    const float* __restrict__ x, const int* __restrict__ tok,
    __bf16* __restrict__ inp)
{
    const int row = blockIdx.x;
    const int t   = threadIdx.x;
    const int tk  = tok[row];
    const float4 v = ((const float4*)(x + (size_t)tk * CDIM))[t];
    bf16x4 o;
    o[0] = (__bf16)v.x; o[1] = (__bf16)v.y; o[2] = (__bf16)v.z; o[3] = (__bf16)v.w;
    *(bf16x4*)(inp + (size_t)row * CDIM + t * 4) = o;
}

// ---------------------------------------------------------------------------
// 320x128 8-wave (4M x 2N) MFMA GEMM, m201-style 2-barrier phases.
//   Exact grid quantization: M=10240/320=32 tiles; GEMM1 grid 1024 (4 rounds),
//   GEMM2 grid 256 (1 round).
//   LDS 112KiB: A dbuf 2x40KB @0, B dbuf 2x16KB @81920. XOR-swizzle
//   (byte ^= (row&7)<<4) via pre-swizzled global source, linear LDS dest.
//   Per K-tile(64): 2 phases x {9 ds_read -> barrier -> lgkm0 -> 20 MFMA ->
//   barrier}; all 7 T+1 gloads issued at P1; vmcnt(0) at tile end (free).
// ---------------------------------------------------------------------------
#define MFMA_BF16 __builtin_amdgcn_mfma_f32_16x16x32_bf16
#define DSR(dst, addr, IMM) \
    asm volatile("ds_read_b128 %0, %1 offset:" #IMM : "=v"(dst) : "v"(addr))
#define WLG0()  asm volatile("s_waitcnt lgkmcnt(0)" ::: "memory")
#define WVM0()  asm volatile("s_waitcnt vmcnt(0)" ::: "memory")
#define SB0()   __builtin_amdgcn_sched_barrier(0)

#define CLUSTER20()                                                           \
    __builtin_amdgcn_s_setprio(1);                                            \
    _Pragma("unroll")                                                         \
    for (int m = 0; m < 5; ++m) {                                             \
        _Pragma("unroll")                                                     \
        for (int n = 0; n < 4; ++n)                                           \
            acc[m][n] = MFMA_BF16(fb[n], fa[m], acc[m][n], 0, 0, 0);          \
    }                                                                         \
    __builtin_amdgcn_s_setprio(0);

template <bool GELU>
__global__ __launch_bounds__(512, 2) void k_gemm8(
    const __bf16* __restrict__ Aall, const __bf16* __restrict__ Ball,
    const float* __restrict__ biasAll, __bf16* __restrict__ Call,
    int Ktot, int Ntot, int NBN, int mtPerE)
{
    __shared__ char lds[114688];   // A: 2*40960 @0 ; B: 2*16384 @81920

    const int NK  = Ktot >> 6;
    const int cpx = gridDim.x >> 3;                 // grid % 8 == 0 by caller
    const int id  = blockIdx.x;
    const int sid = (id & 7) * cpx + (id >> 3);     // bijective XCD swizzle
    const int bm  = sid / NBN, bn = sid % NBN;
    const int e   = bm / mtPerE;

    const size_t row0 = (size_t)bm * 320;
    const int    col0 = bn * 128;

    const int tid = threadIdx.x;
    const int w   = tid >> 6, l = tid & 63;
    const int wr  = w >> 1, wc = w & 1;             // 4M x 2N wave grid
    const int lr  = l & 15, hi = l >> 4;

    // ---- staging constants ----
    const int srow = (w << 3) + (l >> 3);                  // 0..63
    const int kf   = ((l & 7) ^ (l >> 3)) << 3;            // pre-swizzled k elems
    const __bf16* pA = Aall + (row0 + srow) * (size_t)Ktot + kf;
    const __bf16* pB = Ball + ((size_t)e * Ntot + col0 + srow) * (size_t)Ktot + kf;
    const size_t rstep = (size_t)64 * Ktot;
    const unsigned L0  = (unsigned)(size_t)(LAS char*)lds;
    const unsigned dA0 = L0 + w * 1024;                    // +h*8192, h=0..4
    const unsigned dB0 = L0 + 81920 + w * 1024;            // +h*8192, h=0..1

    auto STAGE_ALL = [&](unsigned abufo, unsigned bbufo, int kt) {
        const __bf16* ga = pA + (size_t)kt * 64;
        const __bf16* gb = pB + (size_t)kt * 64;
#pragma unroll
        for (int h = 0; h < 5; ++h)
            __builtin_amdgcn_global_load_lds(
                (const GAS void*)(ga + h * rstep),
                (LAS void*)(size_t)(dA0 + abufo + h * 8192), 16, 0, 0);
#pragma unroll
        for (int h = 0; h < 2; ++h)
            __builtin_amdgcn_global_load_lds(
                (const GAS void*)(gb + h * rstep),
                (LAS void*)(size_t)(dB0 + bbufo + h * 8192), 16, 0, 0);
    };

    // ---- ds_read lane constants (swizzled) ----
    const unsigned swz = (l & 7) << 4;
    const unsigned kb0 = ((unsigned)(hi << 4)) ^ swz;
    const unsigned kb1 = ((unsigned)(64 + (hi << 4))) ^ swz;
    const unsigned AbaseR = L0 + (unsigned)(wr * 80 + lr) * 128;
    const unsigned BbaseR = L0 + 81920 + (unsigned)(wc * 64 + lr) * 128;

    // ---- prologue: stage tile 0 into buf 0 ----
    STAGE_ALL(0, 0, 0);
    WVM0();
    __builtin_amdgcn_s_barrier();
    SB0();

    f32x4 acc[5][4] = {};
    bf16x8 fa[5], fb[4];

    unsigned ab = 0, bb = 0;       // buffer byte offsets
    for (int T = 0; T < NK; ++T) {
        const unsigned va0 = AbaseR + ab + kb0, va1 = AbaseR + ab + kb1;
        const unsigned vb0 = BbaseR + bb + kb0, vb1 = BbaseR + bb + kb1;

        // ---- phase 1: k0 frags + full T+1 staging ----
        DSR(fa[0], va0, 0);    DSR(fa[1], va0, 2048); DSR(fa[2], va0, 4096);
        DSR(fa[3], va0, 6144); DSR(fa[4], va0, 8192);
        DSR(fb[0], vb0, 0);    DSR(fb[1], vb0, 2048);
        DSR(fb[2], vb0, 4096); DSR(fb[3], vb0, 6144);
        if (T + 1 < NK) STAGE_ALL(ab ^ 40960u, bb ^ 16384u, T + 1);
        __builtin_amdgcn_s_barrier();
        WLG0(); SB0();
        CLUSTER20()
        __builtin_amdgcn_s_barrier();
        SB0();

        // ---- phase 2: k1 frags ----
        DSR(fa[0], va1, 0);    DSR(fa[1], va1, 2048); DSR(fa[2], va1, 4096);
        DSR(fa[3], va1, 6144); DSR(fa[4], va1, 8192);
        DSR(fb[0], vb1, 0);    DSR(fb[1], vb1, 2048);
        DSR(fb[2], vb1, 4096); DSR(fb[3], vb1, 6144);
        __builtin_amdgcn_s_barrier();
        WLG0(); SB0();
        CLUSTER20()
        WVM0();                 // T+1 loads landed (issued ~1 tile ago)
        __builtin_amdgcn_s_barrier();
        SB0();

        ab ^= 40960u; bb ^= 16384u;
    }

    // ---- epilogue: row = m*16 + lr, col = n*16 + hi*4 + i (bf16x4 stores) ----
    const size_t crow0 = row0 + (size_t)wr * 80;
    const int    ccol0 = col0 + wc * 64;
#pragma unroll
    for (int n = 0; n < 4; ++n) {
        float bbv[4] = {0.f, 0.f, 0.f, 0.f};
        if (GELU) {
            const float4 b4 = *(const float4*)(biasAll + (size_t)e * Ntot
                                               + ccol0 + n * 16 + hi * 4);
            bbv[0] = b4.x; bbv[1] = b4.y; bbv[2] = b4.z; bbv[3] = b4.w;
        }
#pragma unroll
        for (int m = 0; m < 5; ++m) {
            const f32x4 v = acc[m][n];
            bf16x4 o;
#pragma unroll
            for (int i = 0; i < 4; ++i) {
                float t = v[i];
                if (GELU) {
                    t += bbv[i];
                    const float u  = 0.7978845608028654f * (t + 0.044715f * t * t * t);
                    const float ex = __expf(2.f * u);
                    t = t * (1.f - 1.f / (ex + 1.f));   // 0.5t(1+tanh u)
                }
                o[i] = (__bf16)t;
            }
            *(bf16x4*)(Call + (crow0 + m * 16 + lr) * (size_t)Ntot
                       + ccol0 + n * 16 + hi * 4) = o;
        }
    }
}

// ---------------------------------------------------------------------------
// Combine: y[n][c] = sum_k gate * (out[slot][c] + b2[e][c]); writes all of y.
// ---------------------------------------------------------------------------
__global__ __launch_bounds__(256) void k_combine(
    const __bf16* __restrict__ outb, const int* __restrict__ slot,
    const float* __restrict__ gates, const int* __restrict__ tidx,
    const float* __restrict__ b2, float* __restrict__ y)
{
    const int n = blockIdx.x;
    const int t = threadIdx.x;
    const int c = t * 4;
    float r0 = 0.f, r1 = 0.f, r2 = 0.f, r3 = 0.f;
#pragma unroll
    for (int k = 0; k < KTOP; ++k) {
        const int s = slot[n * 2 + k];
        if (s < 0) continue;
        const float g = gates[n * 2 + k];
        const int   e = tidx[n * 2 + k];
        const bf16x4 v = *(const bf16x4*)(outb + (size_t)s * CDIM + c);
        const float4 bb = *(const float4*)(b2 + (size_t)e * CDIM + c);
        r0 += g * ((float)v[0] + bb.x);
        r1 += g * ((float)v[1] + bb.y);
        r2 += g * ((float)v[2] + bb.z);
        r3 += g * ((float)v[3] + bb.w);
    }
    float4 o = make_float4(r0, r1, r2, r3);
    *(float4*)(y + (size_t)n * CDIM + c) = o;
}

// ---------------------------------------------------------------------------
extern "C" void kernel_launch(void* const* d_in, const int* in_sizes, int n_in,
                              void* d_out, int out_size, void* d_ws, size_t ws_size,
                              hipStream_t stream)
{
    const float* x  = (const float*)d_in[0];
    const float* rw = (const float*)d_in[1];
    const float* rb = (const float*)d_in[2];
    const float* w1 = (const float*)d_in[3];
    const float* b1 = (const float*)d_in[4];
    const float* w2 = (const float*)d_in[5];
    const float* b2 = (const float*)d_in[6];
    float* y = (float*)d_out;

    char* ws = (char*)d_ws;
    size_t off = 0;
    auto alloc = [&](size_t bytes) -> void* {
        void* p = ws + off;
        off = (off + bytes + 255) & ~(size_t)255;
        return p;
    };
    __bf16* w1t  = (__bf16*)alloc((size_t)NE * CDIM * HDIM * 2);   // [E][H][C]
    __bf16* w2t  = (__bf16*)alloc((size_t)NE * CDIM * HDIM * 2);   // [E][C][H]
    __bf16* inp  = (__bf16*)alloc((size_t)NE * CAPE * CDIM * 2);   // [E*cap][C]
    __bf16* hbuf = (__bf16*)alloc((size_t)NE * CAPE * HDIM * 2);   // [E*cap][H]
    __bf16* outb = (__bf16*)alloc((size_t)NE * CAPE * CDIM * 2);   // [E*cap][C]
    float*  probs = (float*)alloc((size_t)NTOK * NE * 4);
    float*  gates = (float*)alloc((size_t)NTOK * 2 * 4);
    int*    tidx  = (int*)alloc((size_t)NTOK * 2 * 4);
    int*    slot  = (int*)alloc((size_t)NTOK * 2 * 4);
    int*    tok   = (int*)alloc((size_t)NE * CAPE * 4);

    // 1. weight conversion (transposed to B^T layout, bf16)
    k_transpose_bf16<<<dim3(HDIM / 32, CDIM / 32, NE), 256, 0, stream>>>(
        w1, w1t, CDIM, HDIM);
    k_transpose_bf16<<<dim3(CDIM / 32, HDIM / 32, NE), 256, 0, stream>>>(
        w2, w2t, HDIM, CDIM);

    // 2. router
    k_router<<<NTOK / 4, 256, 0, stream>>>(x, rw, rb, probs, gates, tidx);

    // 3. dispatch scan + aux loss (single block, exact FCFS order)
    k_scan<<<1, 256, 0, stream>>>(tidx, probs, slot, tok, y + (size_t)NTOK * CDIM);

    // 4. gather expert inputs (bf16)
    k_gather<<<NE * CAPE, 256, 0, stream>>>(x, tok, inp);

    // 5. expert FFN — 320x128-tile MFMA GEMMs, exact grid quantization
    //    GEMM1: 32 m-tiles x 32 n-tiles = 1024 blocks (4.0 rounds)
    k_gemm8<true><<<dim3((NTOK * KTOP * 10 / 16 / 320) * (HDIM / 128)), 512, 0, stream>>>(
        inp, w1t, b1, hbuf, CDIM, HDIM, HDIM / 128, 4);
    //    GEMM2: 32 x 8 = 256 blocks (1.0 round)
    k_gemm8<false><<<dim3((NTOK * KTOP * 10 / 16 / 320) * (CDIM / 128)), 512, 0, stream>>>(
        hbuf, w2t, nullptr, outb, HDIM, CDIM, CDIM / 128, 4);

    // 6. combine back to tokens (+aux already written by scan)
    k_combine<<<NTOK, 256, 0, stream>>>(outb, slot, gates, tidx, b2, y);
}